// Round 3
// baseline (6173.615 us; speedup 1.0000x reference)
//
#include <hip/hip_runtime.h>
#include <hip/hip_fp16.h>

// Wavefront-pipelined 20-layer ReLU RNN for MI355X — round 15.
// Base = round 14 (1131us; r12 = 1104us). Model after r13/r14: the LDS pipe
// is the serialized resource (~2500 of 2830 cy/step: 128 b128 fragment
// reads + writes + 560cy conflicts). Change: remove bufX staging entirely.
// The XP burst's B-operand (X fragments) is prefetched from the ring
// (global, L3-resident) DIRECTLY in MFMA-fragment order into registers
// (xf[4][8] u64-pairs = 64 VGPR), one superstep ahead (loaded at j1,
// consumed at next superstep's j0; 3 steps of slack covers L3 latency).
// This removes per step: 64 LDS b128 X-reads (~768cy), unscramble writes,
// and their conflicts — shifting the traffic to the idle VMEM pipe.
// Sync: mycons publish moves j0 -> j1 (after bar_full drains all waves'
// ring loads, slot s is then truly free). Prologue waits prod>=1 (not 2).
// Arithmetic is bit-identical to r12/r14.

#define B_    128
#define T_    784
#define H_    256
#define L_    20
#define C_    10
#define G_    8      // batch slices
#define BM_   16     // batch rows per block
#define S_    4      // timesteps per superstep / ring slot
#define NS_   196    // T_/S_
#define SW_   280    // LDS row stride in halves (140 dwords = 12 mod 32)
#define RQWS_ 4096   // u64 words per ring slot (4 x 16 x 256 halves = 32KB)
#define TPB_  512

typedef _Float16 v8h __attribute__((ext_vector_type(8)));
typedef _Float16 v4h __attribute__((ext_vector_type(4)));
typedef float    v4f __attribute__((ext_vector_type(4)));
typedef unsigned long long u64;

union U64H { u64 u; _Float16 h[4]; };
union F16x8 { u64 u[2]; v8h v; };

// Raw barrier, LDS-ordering only: each wave drains its own ds ops, then
// rendezvous. No vmcnt drain -> ring loads/stores stay in flight.
__device__ __forceinline__ void bar_lds() {
    asm volatile("s_waitcnt lgkmcnt(0)" ::: "memory");
    __builtin_amdgcn_s_barrier();
    asm volatile("" ::: "memory");
}
// Full drain barrier: once per superstep (top of j==1). After it, every
// wave's ring loads (slot s) and exports (slot s-1) are complete ->
// safe to publish mycons=s+1 and myprod=s.
__device__ __forceinline__ void bar_full() {
    asm volatile("s_waitcnt vmcnt(0) lgkmcnt(0)" ::: "memory");
    __builtin_amdgcn_s_barrier();
    asm volatile("" ::: "memory");
}

__global__ __launch_bounds__(TPB_, 2)
void rnn_wavefront(const float* __restrict__ x,
                   const float* __restrict__ W_ih0,
                   const float* __restrict__ b_ih0,
                   const float* __restrict__ W_ih,
                   const float* __restrict__ b_ih,
                   const float* __restrict__ W_hh,
                   const float* __restrict__ b_hh,
                   const float* __restrict__ W_fc,
                   const float* __restrict__ b_fc,
                   float* __restrict__ out,
                   unsigned* __restrict__ prod,    // [L_][G_] supersteps complete
                   unsigned* __restrict__ cons,    // [L_][G_] supersteps consumed
                   u64* __restrict__ ring,         // [L_][G_][R][RQWS_]
                   int rmask)                      // R-1, R power of two
{
    const int l    = blockIdx.x >> 3;
    const int g    = blockIdx.x & 7;
    const int tid  = threadIdx.x;
    const int lane = tid & 63;
    const int wave = tid >> 6;          // 0..7
    const int quad = lane >> 4;
    const int s16  = lane & 15;
    const int nbase = wave * 32;        // each wave owns 32 output columns
    const int m_e  = tid >> 5;          // export row (0..15)
    const int n_e  = (tid & 31) * 8;    // export col base (0..248)

    __shared__ __align__(16) _Float16 lH[2][BM_][SW_];     // own h, ping-pong

    for (int i = tid; i < 2 * BM_ * SW_; i += TPB_) (&lH[0][0][0])[i] = (_Float16)0.f;

    // ---- weight fragments: lane holds W[n = nbase+nt*16+s16][k = kt*32+quad*8 ..]
    v8h wf[16][2];
#pragma unroll
    for (int kt = 0; kt < 16; ++kt) {
        const int k0 = kt * 32 + quad * 8;
#pragma unroll
        for (int nt = 0; nt < 2; ++nt) {
            const int j = nbase + nt * 16 + s16;
            v8h w;
            if (kt < 8) {
                if (l == 0) {
#pragma unroll
                    for (int i = 0; i < 8; ++i) w[i] = (_Float16)0.f;
                } else {
                    const float* src = &W_ih[(((size_t)(l - 1) * H_) + j) * H_ + k0];
#pragma unroll
                    for (int i = 0; i < 8; ++i) w[i] = (_Float16)src[i];
                }
            } else {
                const float* src = &W_hh[(((size_t)l * H_) + j) * H_ + (k0 - 256)];
#pragma unroll
                for (int i = 0; i < 8; ++i) w[i] = (_Float16)src[i];
            }
            wf[kt][nt] = w;
        }
    }

    // bias/w0 indexed by the transposed C/D layout: lane owns rows
    // n = nbase + nt*16 + quad*4 + r  (r = 0..3), col m = s16.
    float bias[2][4], w0v[2][4];
#pragma unroll
    for (int nt = 0; nt < 2; ++nt)
#pragma unroll
        for (int r = 0; r < 4; ++r) {
            const int j = nbase + nt * 16 + quad * 4 + r;
            bias[nt][r] = b_hh[l * H_ + j] + ((l == 0) ? b_ih0[j] : b_ih[(l - 1) * H_ + j]);
            w0v[nt][r]  = (l == 0) ? W_ih0[j] : 0.f;
        }

    unsigned* upprod = prod + ((l > 0 ? l - 1 : 0) * G_ + g);
    unsigned* myprod = prod + (l * G_ + g);
    unsigned* mycons = cons + (l * G_ + g);
    unsigned* dncons = cons + (((l < L_ - 1) ? l + 1 : l) * G_ + g);
    const unsigned R = (unsigned)rmask + 1u;
    u64* myring = ring + ((size_t)(l * G_ + g) * (size_t)R) * RQWS_;
    u64* upring = ring + ((size_t)((l > 0 ? l - 1 : 0) * G_ + g) * (size_t)R) * RQWS_;

    unsigned pSeen = 0, cSeen = 0;         // tid64 / tid128 private
    const size_t eidx = (size_t)m_e * 64 + (size_t)(tid & 31) * 2;  // u64 idx in slot
    // fragment u64 base index for this lane within a slot-step: row s16,
    // col kt*32+quad*8 -> u64 idx = s16*64 + kt*8 + quad*2
    const size_t fbase = (size_t)s16 * 64 + (size_t)quad * 2;

    // X fragments for the current superstep, loaded in MFMA operand order.
    F16x8 xf[S_][8];

    // ---- prologue (l>0): wait prod>=1, load slot 0 fragments -> regs ----
    if (l > 0) {
        if (tid == 64) {
            while (pSeen < 1u) {
                pSeen = __hip_atomic_load(upprod, __ATOMIC_RELAXED,
                                          __HIP_MEMORY_SCOPE_AGENT);
                if (pSeen < 1u) __builtin_amdgcn_s_sleep(2);
            }
        }
        __syncthreads();
#pragma unroll
        for (int jj = 0; jj < S_; ++jj)
#pragma unroll
            for (int kt = 0; kt < 8; ++kt) {
                const size_t fidx = (size_t)jj * 1024 + fbase + kt * 8;
                xf[jj][kt].u[0] = __hip_atomic_load(upring + fidx,
                                      __ATOMIC_RELAXED, __HIP_MEMORY_SCOPE_AGENT);
                xf[jj][kt].u[1] = __hip_atomic_load(upring + fidx + 1,
                                      __ATOMIC_RELAXED, __HIP_MEMORY_SCOPE_AGENT);
            }
    }

    for (int s = 0; s < NS_; ++s) {
        const bool pfOK = (l > 0) && (s + 1 < NS_);
        v4h XPh[S_][2];   // hoisted X-half results + bias, fp16 (transposed layout)

#pragma unroll
        for (int j = 0; j < S_; ++j) {
            const int t = S_ * s + j;
            // step barrier: LDS-only, except j==1 (full drain, guards the
            // publishes just below -> slot s-1 exports + slot s loads done).
            if (j == 1) bar_full(); else bar_lds();

            if (j == 0) {
                if (tid == 64 && pfOK) {            // guards pf of slot s+1 at j1
                    const unsigned tgt = (unsigned)(s + 2);
                    while (pSeen < tgt) {
                        pSeen = __hip_atomic_load(upprod, __ATOMIC_RELAXED,
                                                  __HIP_MEMORY_SCOPE_AGENT);
                        if (pSeen < tgt) __builtin_amdgcn_s_sleep(2);
                    }
                }
                if (tid == 128 && l < L_ - 1 && s >= (int)R) {  // guards exports into slot s
                    const unsigned tgt = (unsigned)(s - (int)R + 1);
                    while (cSeen < tgt) {
                        cSeen = __hip_atomic_load(dncons, __ATOMIC_RELAXED,
                                                  __HIP_MEMORY_SCOPE_AGENT);
                        if (cSeen < tgt) __builtin_amdgcn_s_sleep(2);
                    }
                }

                // ---- XP burst (transposed): XP[jj] = W_ih · X(4s+jj)^T + bias
                //      B-operand straight from xf registers (no LDS). ----
                if (l > 0) {
                    v4f xpa[S_][2];
#pragma unroll
                    for (int jj = 0; jj < S_; ++jj)
#pragma unroll
                        for (int nt = 0; nt < 2; ++nt)
                            xpa[jj][nt] = (v4f){bias[nt][0], bias[nt][1],
                                                bias[nt][2], bias[nt][3]};
#pragma unroll
                    for (int jj = 0; jj < S_; ++jj) {
#pragma unroll
                        for (int kt = 0; kt < 8; ++kt) {
                            v8h a = xf[jj][kt].v;
                            xpa[jj][0] = __builtin_amdgcn_mfma_f32_16x16x32_f16(wf[kt][0], a, xpa[jj][0], 0, 0, 0);
                            xpa[jj][1] = __builtin_amdgcn_mfma_f32_16x16x32_f16(wf[kt][1], a, xpa[jj][1], 0, 0, 0);
                        }
                    }
#pragma unroll
                    for (int jj = 0; jj < S_; ++jj)
#pragma unroll
                        for (int nt = 0; nt < 2; ++nt)
#pragma unroll
                            for (int r = 0; r < 4; ++r)
                                XPh[jj][nt][r] = (_Float16)xpa[jj][nt][r];
                } else {
                    // layer 0: XP[n][m] = bias[n] + x[m]*w0[n]; lane col m = s16
#pragma unroll
                    for (int jj = 0; jj < S_; ++jj) {
                        const float xv = x[(size_t)(g * BM_ + s16) * T_ + (S_ * s + jj)];
#pragma unroll
                        for (int nt = 0; nt < 2; ++nt)
#pragma unroll
                            for (int r = 0; r < 4; ++r)
                                XPh[jj][nt][r] = (_Float16)(bias[nt][r] + xv * w0v[nt][r]);
                    }
                }
            }

            if (j == 1) {
                // after bar_full: all waves' slot-s ring loads are complete
                // -> slot s free; slot s-1 exports drained -> publish prod.
                if (tid == 0 && l > 0)
                    __hip_atomic_store(mycons, (unsigned)(s + 1), __ATOMIC_RELAXED,
                                       __HIP_MEMORY_SCOPE_AGENT);
                if (tid == 0 && l < L_ - 1 && s >= 1)
                    __hip_atomic_store(myprod, (unsigned)s, __ATOMIC_RELAXED,
                                       __HIP_MEMORY_SCOPE_AGENT); // slots 0..s-1 done
                if (pfOK) {   // prefetch slot s+1 fragments -> xf (used at next j0)
                    const u64* base = upring + (size_t)((s + 1) & rmask) * RQWS_;
#pragma unroll
                    for (int jj = 0; jj < S_; ++jj)
#pragma unroll
                        for (int kt = 0; kt < 8; ++kt) {
                            const size_t fidx = (size_t)jj * 1024 + fbase + kt * 8;
                            xf[jj][kt].u[0] = __hip_atomic_load(base + fidx,
                                                  __ATOMIC_RELAXED, __HIP_MEMORY_SCOPE_AGENT);
                            xf[jj][kt].u[1] = __hip_atomic_load(base + fidx + 1,
                                                  __ATOMIC_RELAXED, __HIP_MEMORY_SCOPE_AGENT);
                        }
                }
            }

            // ---- export h(t-1) (lag 1 step; lH[t&1] holds h(t-1)) ----
            if (l < L_ - 1 && t > 0) {
                u64 e0 = *(const u64*)&lH[t & 1][m_e][n_e];
                u64 e1 = *(const u64*)&lH[t & 1][m_e][n_e + 4];
                u64* d = myring + (size_t)(((t - 1) >> 2) & rmask) * RQWS_
                                + (size_t)((t - 1) & 3) * 1024 + eidx;
                __hip_atomic_store(d,     e0, __ATOMIC_RELAXED, __HIP_MEMORY_SCOPE_AGENT);
                __hip_atomic_store(d + 1, e1, __ATOMIC_RELAXED, __HIP_MEMORY_SCOPE_AGENT);
            }

            // ---- serial h-MFMA (transposed): D = W_hh · h(t-1)^T, 16 MFMA ----
            v4f acc0 = (v4f){0.f, 0.f, 0.f, 0.f};
            v4f acc1 = (v4f){0.f, 0.f, 0.f, 0.f};
#pragma unroll
            for (int kt = 8; kt < 16; ++kt) {
                v8h a = *(const v8h*)&lH[t & 1][s16][(kt - 8) * 32 + quad * 8];
                acc0 = __builtin_amdgcn_mfma_f32_16x16x32_f16(wf[kt][0], a, acc0, 0, 0, 0);
                acc1 = __builtin_amdgcn_mfma_f32_16x16x32_f16(wf[kt][1], a, acc1, 0, 0, 0);
            }

            // ---- epilogue: relu(XP + acc) -> lH[(t+1)&1]; lane holds
            // D[n = nbase+nt*16+quad*4+r][m = s16] -> ONE b64 write per nt ----
#pragma unroll
            for (int nt = 0; nt < 2; ++nt) {
                const v4f av = nt ? acc1 : acc0;
                U64H pk;
#pragma unroll
                for (int r = 0; r < 4; ++r) {
                    float v = (float)XPh[j][nt][r] + av[r];
                    v = fmaxf(v, 0.f);
                    pk.h[r] = (_Float16)v;
                }
                *(u64*)&lH[(t + 1) & 1][s16][nbase + nt * 16 + quad * 4] = pk.u;
            }
        }
    }

    if (l < L_ - 1) {
        // tail: export h(T-1) (in lH[0]: (783+1)&1), drain, publish all done
        u64 e0 = *(const u64*)&lH[0][m_e][n_e];
        u64 e1 = *(const u64*)&lH[0][m_e][n_e + 4];
        u64* d = myring + (size_t)(((T_ - 1) >> 2) & rmask) * RQWS_
                        + (size_t)3 * 1024 + eidx;
        __hip_atomic_store(d,     e0, __ATOMIC_RELAXED, __HIP_MEMORY_SCOPE_AGENT);
        __hip_atomic_store(d + 1, e1, __ATOMIC_RELAXED, __HIP_MEMORY_SCOPE_AGENT);
        __syncthreads();   // full drain (vmcnt(0)) before publishing final prod
        if (tid == 0)
            __hip_atomic_store(myprod, (unsigned)NS_, __ATOMIC_RELAXED,
                               __HIP_MEMORY_SCOPE_AGENT);
    } else {
        __syncthreads();
        // final FC: out[b] = h_T[b] @ W_fc^T + b_fc; h_T in lH[0]
        if (tid < BM_ * C_) {
            const int bl = tid / C_;
            const int c  = tid % C_;
            float sum = b_fc[c];
            for (int k = 0; k < H_; ++k) sum += (float)lH[0][bl][k] * W_fc[c * H_ + k];
            out[(size_t)(g * BM_ + bl) * C_ + c] = sum;
        }
    }
}

extern "C" void kernel_launch(void* const* d_in, const int* in_sizes, int n_in,
                              void* d_out, int out_size, void* d_ws, size_t ws_size,
                              hipStream_t stream) {
    const float* x     = (const float*)d_in[0];
    const float* W_ih0 = (const float*)d_in[1];
    const float* b_ih0 = (const float*)d_in[2];
    const float* W_ih  = (const float*)d_in[3];
    const float* b_ih  = (const float*)d_in[4];
    const float* W_hh  = (const float*)d_in[5];
    const float* b_hh  = (const float*)d_in[6];
    const float* W_fc  = (const float*)d_in[7];
    const float* b_fc  = (const float*)d_in[8];
    float* out = (float*)d_out;

    const size_t cntBytes = (size_t)L_ * G_ * sizeof(unsigned);   // 640 B each
    unsigned* prod = (unsigned*)d_ws;
    unsigned* cons = (unsigned*)((char*)d_ws + cntBytes);
    u64* ring      = (u64*)((char*)d_ws + 2 * cntBytes);

    // ring slots per link, by available workspace (32 KB per slot per link)
    const size_t slotBytes = (size_t)RQWS_ * 8;                   // 32 KB
    const size_t base = 2 * cntBytes;
    int R = 4;                                                    // 21 MB
    if (ws_size >= base + (size_t)L_ * G_ * 16 * slotBytes) R = 16;      // 84 MB
    else if (ws_size >= base + (size_t)L_ * G_ * 8 * slotBytes) R = 8;   // 42 MB

    hipMemsetAsync(d_ws, 0, 2 * cntBytes, stream);

    rnn_wavefront<<<dim3(L_ * G_), dim3(TPB_), 0, stream>>>(
        x, W_ih0, b_ih0, W_ih, b_ih, W_hh, b_hh, W_fc, b_fc,
        out, prod, cons, ring, R - 1);
}

// Round 4
// 1127.256 us; speedup vs baseline: 5.4767x; 5.4767x over previous
//
#include <hip/hip_runtime.h>
#include <hip/hip_fp16.h>

// Wavefront-pipelined 20-layer ReLU RNN for MI355X — round 16.
// Base = r12/r14 (1104/1131us). Model: LDS-throughput-bound (~85% busy);
// the 8x cross-wave re-read of the shared MFMA B-operand (h and X
// fragments) is the dominant term (128 b128/step/CU).
// Change: producer/consumer WAVE SPECIALIZATION. Waves 0-3 ("h-waves",
// nt=4, 64 n each) run the serial h-GEMM per step. Waves 4-7 ("X-waves",
// nt=4) compute XP for superstep s+1 (one jj per step) and write the
// f16 results to a new xps LDS buffer (ping-pong by superstep parity).
// Fragment reads drop 8x->4x amplification: 64 b128/step/CU instead of
// 128. Each SIMD hosts 1 h-wave + 1 X-wave (waves round-robin SIMDs),
// so the h-chain latency r13 exposed is hidden by the co-resident
// X-wave. bufX double-buffered: slot s+2 staged during s via r12's
// proven j1-load->j3-write reg indirection (extra j3 barrier removed).
// XP is rounded to f16 exactly as before -> bit-identical arithmetic.
// r15's fragment-order ring reads (8GB HBM flood) reverted to staged.

#define B_    128
#define T_    784
#define H_    256
#define L_    20
#define C_    10
#define G_    8      // batch slices
#define BM_   16     // batch rows per block
#define S_    4      // timesteps per superstep / ring slot
#define NS_   196    // T_/S_
#define SW_   280    // LDS row stride in halves (140 dwords = 12 mod 32)
#define XSW_  260    // xps row stride in halves (130 dwords = 2 mod 32)
#define RQWS_ 4096   // u64 words per ring slot (4 x 16 x 256 halves = 32KB)
#define TPB_  512
#define HW_   4      // h-waves (waves 0..3); waves 4..7 are X-waves
#define NT_   4      // 16-col n-tiles per wave (both roles)

typedef _Float16 v8h __attribute__((ext_vector_type(8)));
typedef _Float16 v4h __attribute__((ext_vector_type(4)));
typedef float    v4f __attribute__((ext_vector_type(4)));
typedef unsigned long long u64;

union U64H { u64 u; _Float16 h[4]; };

// LDS-ordering barrier: drain own ds ops, rendezvous. vmem stays in flight.
__device__ __forceinline__ void bar_lds() {
    asm volatile("s_waitcnt lgkmcnt(0)" ::: "memory");
    __builtin_amdgcn_s_barrier();
    asm volatile("" ::: "memory");
}
// Full drain barrier (once per superstep, top of j==1): all waves' ring
// exports (slot s-1) complete -> safe to publish myprod=s after it.
__device__ __forceinline__ void bar_full() {
    asm volatile("s_waitcnt vmcnt(0) lgkmcnt(0)" ::: "memory");
    __builtin_amdgcn_s_barrier();
    asm volatile("" ::: "memory");
}

__global__ __launch_bounds__(TPB_, 2)
void rnn_wavefront(const float* __restrict__ x,
                   const float* __restrict__ W_ih0,
                   const float* __restrict__ b_ih0,
                   const float* __restrict__ W_ih,
                   const float* __restrict__ b_ih,
                   const float* __restrict__ W_hh,
                   const float* __restrict__ b_hh,
                   const float* __restrict__ W_fc,
                   const float* __restrict__ b_fc,
                   float* __restrict__ out,
                   unsigned* __restrict__ prod,    // [L_][G_] supersteps complete
                   unsigned* __restrict__ cons,    // [L_][G_] supersteps consumed
                   u64* __restrict__ ring,         // [L_][G_][R][RQWS_]
                   int rmask)                      // R-1, R power of two
{
    const int l    = blockIdx.x >> 3;
    const int g    = blockIdx.x & 7;
    const int tid  = threadIdx.x;
    const int lane = tid & 63;
    const int wave = tid >> 6;          // 0..7
    const bool hwv = wave < HW_;        // h-wave vs X-wave
    const int wsub = hwv ? wave : wave - HW_;
    const int quad = lane >> 4;
    const int s16  = lane & 15;
    const int nbase = wsub * 64;        // 64 output columns per wave (both roles)
    const int m_e  = tid >> 5;          // export/staging row (0..15)
    const int n_e  = (tid & 31) * 8;    // export/staging col base (0..248)

    // slot q lives in bufX[q&1]; staged during superstep q-2.
    __shared__ __align__(16) _Float16 bufX[2][S_][BM_][SW_];
    __shared__ __align__(16) _Float16 lH[2][BM_][SW_];     // own h, ping-pong
    // xps[p][jj][m][n]: XP for superstep s (p = s&1), f16, written by X-waves
    // during superstep s-1, read by h-waves during superstep s.
    __shared__ __align__(16) _Float16 xps[2][S_][BM_][XSW_];

    for (int i = tid; i < 2 * BM_ * SW_; i += TPB_) (&lH[0][0][0])[i] = (_Float16)0.f;

    // ---- weight fragments: role-split. h-waves: W_hh rows nbase..+63.
    // X-waves: W_ih (l>0). Lane holds W[n = nbase+nt*16+s16][k = kt*32+quad*8..]
    v8h wf[8][NT_];
#pragma unroll
    for (int kt = 0; kt < 8; ++kt) {
        const int k0 = kt * 32 + quad * 8;
#pragma unroll
        for (int nt = 0; nt < NT_; ++nt) {
            const int j = nbase + nt * 16 + s16;
            v8h w;
            if (hwv) {
                const float* src = &W_hh[(((size_t)l * H_) + j) * H_ + k0];
#pragma unroll
                for (int i = 0; i < 8; ++i) w[i] = (_Float16)src[i];
            } else if (l > 0) {
                const float* src = &W_ih[(((size_t)(l - 1) * H_) + j) * H_ + k0];
#pragma unroll
                for (int i = 0; i < 8; ++i) w[i] = (_Float16)src[i];
            } else {
#pragma unroll
                for (int i = 0; i < 8; ++i) w[i] = (_Float16)0.f;
            }
            wf[kt][nt] = w;
        }
    }

    // bias/w0: X-waves only (bias is folded into XP exactly as before).
    float bias[NT_][4], w0v[NT_][4];
    if (!hwv) {
#pragma unroll
        for (int nt = 0; nt < NT_; ++nt)
#pragma unroll
            for (int r = 0; r < 4; ++r) {
                const int j = nbase + nt * 16 + quad * 4 + r;
                bias[nt][r] = b_hh[l * H_ + j] +
                              ((l == 0) ? b_ih0[j] : b_ih[(l - 1) * H_ + j]);
                w0v[nt][r]  = (l == 0) ? W_ih0[j] : 0.f;
            }
    }

    unsigned* upprod = prod + ((l > 0 ? l - 1 : 0) * G_ + g);
    unsigned* myprod = prod + (l * G_ + g);
    unsigned* mycons = cons + (l * G_ + g);
    unsigned* dncons = cons + (((l < L_ - 1) ? l + 1 : l) * G_ + g);
    const unsigned R = (unsigned)rmask + 1u;
    u64* myring = ring + ((size_t)(l * G_ + g) * (size_t)R) * RQWS_;
    u64* upring = ring + ((size_t)((l > 0 ? l - 1 : 0) * G_ + g) * (size_t)R) * RQWS_;

    unsigned pSeen = 0, cSeen = 0;         // tid64 / tid128 private
    const size_t eidx = (size_t)m_e * 64 + (size_t)(tid & 31) * 2;  // u64 idx in slot

    // ---- prologue ----
    if (l > 0) {
        // wait for slots 0 and 1, stage them into bufX[0], bufX[1]
        if (tid == 64) {
            while (pSeen < 2u) {
                pSeen = __hip_atomic_load(upprod, __ATOMIC_RELAXED,
                                          __HIP_MEMORY_SCOPE_AGENT);
                if (pSeen < 2u) __builtin_amdgcn_s_sleep(2);
            }
        }
        __syncthreads();
#pragma unroll
        for (int sl = 0; sl < 2; ++sl)
#pragma unroll
            for (int jj = 0; jj < S_; ++jj) {
                u64 v0 = __hip_atomic_load(upring + (size_t)sl * RQWS_ + (size_t)jj * 1024 + eidx,
                                           __ATOMIC_RELAXED, __HIP_MEMORY_SCOPE_AGENT);
                u64 v1 = __hip_atomic_load(upring + (size_t)sl * RQWS_ + (size_t)jj * 1024 + eidx + 1,
                                           __ATOMIC_RELAXED, __HIP_MEMORY_SCOPE_AGENT);
                *(u64*)&bufX[sl][jj][m_e][n_e]     = v0;
                *(u64*)&bufX[sl][jj][m_e][n_e + 4] = v1;
            }
        __syncthreads();
    }
    // X-waves: compute xps[0] (XP for superstep 0, t = 0..3)
    if (!hwv) {
#pragma unroll
        for (int jj = 0; jj < S_; ++jj) {
            v4f xpa[NT_];
#pragma unroll
            for (int nt = 0; nt < NT_; ++nt)
                xpa[nt] = (v4f){bias[nt][0], bias[nt][1], bias[nt][2], bias[nt][3]};
            if (l > 0) {
#pragma unroll
                for (int kt = 0; kt < 8; ++kt) {
                    v8h a = *(const v8h*)&bufX[0][jj][s16][kt * 32 + quad * 8];
#pragma unroll
                    for (int nt = 0; nt < NT_; ++nt)
                        xpa[nt] = __builtin_amdgcn_mfma_f32_16x16x32_f16(
                                      wf[kt][nt], a, xpa[nt], 0, 0, 0);
                }
            } else {
                const float xv = x[(size_t)(g * BM_ + s16) * T_ + jj];
#pragma unroll
                for (int nt = 0; nt < NT_; ++nt)
#pragma unroll
                    for (int r = 0; r < 4; ++r)
                        xpa[nt][r] = bias[nt][r] + xv * w0v[nt][r];
            }
#pragma unroll
            for (int nt = 0; nt < NT_; ++nt) {
                U64H pk;
#pragma unroll
                for (int r = 0; r < 4; ++r) pk.h[r] = (_Float16)xpa[nt][r];
                *(u64*)&xps[0][jj][s16][nbase + nt * 16 + quad * 4] = pk.u;
            }
        }
    }
    __syncthreads();   // lH zeros + xps[0] visible to all

    for (int s = 0; s < NS_; ++s) {
        const bool stOK = (l > 0) && (s + 2 < NS_);   // stage slot s+2 this superstep
        const bool xOK  = (s + 1 < NS_);              // compute XP for superstep s+1
        u64 pfv[S_][2];

#pragma unroll
        for (int j = 0; j < S_; ++j) {
            const int t = S_ * s + j;
            if (j == 1) bar_full(); else bar_lds();

            if (j == 0) {
                // slot s+1 finished copying during superstep s-1 -> free.
                if (tid == 0 && l > 0) {
                    const unsigned cv = (unsigned)((s + 2 <= NS_) ? s + 2 : NS_);
                    __hip_atomic_store(mycons, cv, __ATOMIC_RELAXED,
                                       __HIP_MEMORY_SCOPE_AGENT);
                }
                if (tid == 64 && stOK) {            // guards pf of slot s+2 at j1
                    const unsigned tgt = (unsigned)(s + 3);
                    while (pSeen < tgt) {
                        pSeen = __hip_atomic_load(upprod, __ATOMIC_RELAXED,
                                                  __HIP_MEMORY_SCOPE_AGENT);
                        if (pSeen < tgt) __builtin_amdgcn_s_sleep(2);
                    }
                }
                if (tid == 128 && l < L_ - 1 && s >= (int)R) {  // guards exports into slot s
                    const unsigned tgt = (unsigned)(s - (int)R + 1);
                    while (cSeen < tgt) {
                        cSeen = __hip_atomic_load(dncons, __ATOMIC_RELAXED,
                                                  __HIP_MEMORY_SCOPE_AGENT);
                        if (cSeen < tgt) __builtin_amdgcn_s_sleep(2);
                    }
                }
            }

            if (j == 1) {
                if (tid == 0 && l < L_ - 1 && s >= 1)
                    __hip_atomic_store(myprod, (unsigned)s, __ATOMIC_RELAXED,
                                       __HIP_MEMORY_SCOPE_AGENT); // slots 0..s-1 done
                if (stOK) {   // prefetch slot s+2 -> regs (written to bufX at j3)
                    const u64* base = upring + (size_t)((s + 2) & rmask) * RQWS_;
#pragma unroll
                    for (int jj = 0; jj < S_; ++jj) {
                        pfv[jj][0] = __hip_atomic_load(base + (size_t)jj * 1024 + eidx,
                                                       __ATOMIC_RELAXED,
                                                       __HIP_MEMORY_SCOPE_AGENT);
                        pfv[jj][1] = __hip_atomic_load(base + (size_t)jj * 1024 + eidx + 1,
                                                       __ATOMIC_RELAXED,
                                                       __HIP_MEMORY_SCOPE_AGENT);
                    }
                }
            }

            // ---- export h(t-1) (lag 1 step; lH[t&1] holds h(t-1)) ----
            if (l < L_ - 1 && t > 0) {
                u64 e0 = *(const u64*)&lH[t & 1][m_e][n_e];
                u64 e1 = *(const u64*)&lH[t & 1][m_e][n_e + 4];
                u64* d = myring + (size_t)(((t - 1) >> 2) & rmask) * RQWS_
                                + (size_t)((t - 1) & 3) * 1024 + eidx;
                __hip_atomic_store(d,     e0, __ATOMIC_RELAXED, __HIP_MEMORY_SCOPE_AGENT);
                __hip_atomic_store(d + 1, e1, __ATOMIC_RELAXED, __HIP_MEMORY_SCOPE_AGENT);
            }

            if (hwv) {
                // ---- h-wave: xph read + serial h-MFMA + epilogue ----
                v4h xph[NT_];
#pragma unroll
                for (int nt = 0; nt < NT_; ++nt)
                    xph[nt] = *(const v4h*)&xps[s & 1][j][s16][nbase + nt * 16 + quad * 4];

                v4f acc[NT_];
#pragma unroll
                for (int nt = 0; nt < NT_; ++nt) acc[nt] = (v4f){0.f, 0.f, 0.f, 0.f};
#pragma unroll
                for (int kt = 0; kt < 8; ++kt) {
                    v8h a = *(const v8h*)&lH[t & 1][s16][kt * 32 + quad * 8];
#pragma unroll
                    for (int nt = 0; nt < NT_; ++nt)
                        acc[nt] = __builtin_amdgcn_mfma_f32_16x16x32_f16(
                                      wf[kt][nt], a, acc[nt], 0, 0, 0);
                }
                // epilogue: relu(XP + acc) -> lH[(t+1)&1]; one b64 per nt
#pragma unroll
                for (int nt = 0; nt < NT_; ++nt) {
                    U64H pk;
#pragma unroll
                    for (int r = 0; r < 4; ++r) {
                        float v = (float)xph[nt][r] + acc[nt][r];
                        v = fmaxf(v, 0.f);
                        pk.h[r] = (_Float16)v;
                    }
                    *(u64*)&lH[(t + 1) & 1][s16][nbase + nt * 16 + quad * 4] = pk.u;
                }
            } else if (xOK) {
                // ---- X-wave: XP[s+1][jj=j] = W_ih · X(4(s+1)+j)^T + bias ----
                v4f xpa[NT_];
#pragma unroll
                for (int nt = 0; nt < NT_; ++nt)
                    xpa[nt] = (v4f){bias[nt][0], bias[nt][1], bias[nt][2], bias[nt][3]};
                if (l > 0) {
#pragma unroll
                    for (int kt = 0; kt < 8; ++kt) {
                        v8h a = *(const v8h*)&bufX[(s + 1) & 1][j][s16][kt * 32 + quad * 8];
#pragma unroll
                        for (int nt = 0; nt < NT_; ++nt)
                            xpa[nt] = __builtin_amdgcn_mfma_f32_16x16x32_f16(
                                          wf[kt][nt], a, xpa[nt], 0, 0, 0);
                    }
                } else {
                    const float xv = x[(size_t)(g * BM_ + s16) * T_ + (S_ * (s + 1) + j)];
#pragma unroll
                    for (int nt = 0; nt < NT_; ++nt)
#pragma unroll
                        for (int r = 0; r < 4; ++r)
                            xpa[nt][r] = bias[nt][r] + xv * w0v[nt][r];
                }
#pragma unroll
                for (int nt = 0; nt < NT_; ++nt) {
                    U64H pk;
#pragma unroll
                    for (int r = 0; r < 4; ++r) pk.h[r] = (_Float16)xpa[nt][r];
                    *(u64*)&xps[(s + 1) & 1][j][s16][nbase + nt * 16 + quad * 4] = pk.u;
                }
            }

            if (j == S_ - 1 && stOK) {
                // write slot s+2 into its bufX parity buffer (read starts next
                // superstep; the j0-top barrier orders it). No extra barrier.
#pragma unroll
                for (int jj = 0; jj < S_; ++jj) {
                    *(u64*)&bufX[s & 1][jj][m_e][n_e]     = pfv[jj][0];
                    *(u64*)&bufX[s & 1][jj][m_e][n_e + 4] = pfv[jj][1];
                }
            }
        }
    }

    if (l < L_ - 1) {
        // tail: export h(T-1) (in lH[0]), drain, publish all done
        u64 e0 = *(const u64*)&lH[0][m_e][n_e];
        u64 e1 = *(const u64*)&lH[0][m_e][n_e + 4];
        u64* d = myring + (size_t)(((T_ - 1) >> 2) & rmask) * RQWS_
                        + (size_t)3 * 1024 + eidx;
        __hip_atomic_store(d,     e0, __ATOMIC_RELAXED, __HIP_MEMORY_SCOPE_AGENT);
        __hip_atomic_store(d + 1, e1, __ATOMIC_RELAXED, __HIP_MEMORY_SCOPE_AGENT);
        __syncthreads();   // full drain (vmcnt(0)) before publishing final prod
        if (tid == 0)
            __hip_atomic_store(myprod, (unsigned)NS_, __ATOMIC_RELAXED,
                               __HIP_MEMORY_SCOPE_AGENT);
    } else {
        __syncthreads();
        // final FC: out[b] = h_T[b] @ W_fc^T + b_fc; h_T in lH[0]
        if (tid < BM_ * C_) {
            const int bl = tid / C_;
            const int c  = tid % C_;
            float sum = b_fc[c];
            for (int k = 0; k < H_; ++k) sum += (float)lH[0][bl][k] * W_fc[c * H_ + k];
            out[(size_t)(g * BM_ + bl) * C_ + c] = sum;
        }
    }
}

extern "C" void kernel_launch(void* const* d_in, const int* in_sizes, int n_in,
                              void* d_out, int out_size, void* d_ws, size_t ws_size,
                              hipStream_t stream) {
    const float* x     = (const float*)d_in[0];
    const float* W_ih0 = (const float*)d_in[1];
    const float* b_ih0 = (const float*)d_in[2];
    const float* W_ih  = (const float*)d_in[3];
    const float* b_ih  = (const float*)d_in[4];
    const float* W_hh  = (const float*)d_in[5];
    const float* b_hh  = (const float*)d_in[6];
    const float* W_fc  = (const float*)d_in[7];
    const float* b_fc  = (const float*)d_in[8];
    float* out = (float*)d_out;

    const size_t cntBytes = (size_t)L_ * G_ * sizeof(unsigned);   // 640 B each
    unsigned* prod = (unsigned*)d_ws;
    unsigned* cons = (unsigned*)((char*)d_ws + cntBytes);
    u64* ring      = (u64*)((char*)d_ws + 2 * cntBytes);

    // ring slots per link, by available workspace (32 KB per slot per link)
    const size_t slotBytes = (size_t)RQWS_ * 8;                   // 32 KB
    const size_t base = 2 * cntBytes;
    int R = 4;                                                    // 21 MB
    if (ws_size >= base + (size_t)L_ * G_ * 16 * slotBytes) R = 16;      // 84 MB
    else if (ws_size >= base + (size_t)L_ * G_ * 8 * slotBytes) R = 8;   // 42 MB

    hipMemsetAsync(d_ws, 0, 2 * cntBytes, stream);

    rnn_wavefront<<<dim3(L_ * G_), dim3(TPB_), 0, stream>>>(
        x, W_ih0, b_ih0, W_ih, b_ih, W_hh, b_hh, W_fc, b_fc,
        out, prod, cons, ring, R - 1);
}